// Round 13
// baseline (1590.519 us; speedup 1.0000x reference)
//
#include <hip/hip_runtime.h>
#include <hip/hip_bf16.h>

#define P_ 50000
#define NL_ 2000
#define NQ_ 6000
#define L_ 8
#define P2L_ 128
#define P2Q_ 64
#define D_ 32
#define ITERS_ 8
#define RA_ 1563  // remap blocks for path-indexed arrays (P_*8/256)
#define RC_ 1500  // remap blocks for p2q pairs (NQ_*P2Q_/256)

typedef __hip_bfloat16 bf16;
typedef unsigned short u16;
typedef unsigned int u32;

__device__ __forceinline__ float bfb2f(u16 u) {
    union { u32 i; float f; } c; c.i = ((u32)u) << 16; return c.f;
}
__device__ __forceinline__ u16 f2bfb(float f) {
    union { bf16 h; u16 u; } c; c.h = __float2bfloat16(f); return c.u;
}
__device__ __forceinline__ u32 pk2(float a, float b) {
    return (u32)f2bfb(a) | ((u32)f2bfb(b) << 16);
}

__device__ __forceinline__ float tanh_fast(float x) {
    return 1.f - 2.f / (__expf(2.f * x) + 1.f);
}
__device__ __forceinline__ float4 tanh4(float4 a) {
    return make_float4(tanh_fast(a.x), tanh_fast(a.y), tanh_fast(a.z), tanh_fast(a.w));
}
__device__ __forceinline__ float4 add4(float4 a, float4 b) {
    return make_float4(a.x + b.x, a.y + b.y, a.z + b.z, a.w + b.w);
}

// butterfly-order replicated state: hr[4s+c] = h[4*(i^s)+c] for this lane's i.
__device__ __forceinline__ void hr_rebuild(float* hr, float4 own) {
    hr[0] = own.x; hr[1] = own.y; hr[2] = own.z; hr[3] = own.w;
#pragma unroll
    for (int c = 0; c < 4; c++)  hr[4 + c]  = __shfl_xor(hr[c], 1, 64);
#pragma unroll
    for (int c = 0; c < 8; c++)  hr[8 + c]  = __shfl_xor(hr[c], 2, 64);
#pragma unroll
    for (int c = 0; c < 16; c++) hr[16 + c] = __shfl_xor(hr[c], 4, 64);
}

// acc += full-h @ W[:,4i..4i+3]; W in LDS at base, offs[s] = (i^s)*128+4i
// split into two 16-deep chains for FMA-latency ILP.
__device__ __forceinline__ float4 matvec32o(const float* hr, const float* base,
                                            const int* offs, float4 acc) {
    float4 acc2 = make_float4(0.f, 0.f, 0.f, 0.f);
#pragma unroll
    for (int s = 0; s < 4; s++) {
        const float* u0 = base + offs[s];
        const float* u1 = base + offs[s + 4];
#pragma unroll
        for (int c = 0; c < 4; c++) {
            const float4 u = *(const float4*)(u0 + 32 * c);
            const float hk = hr[4 * s + c];
            acc.x += hk * u.x; acc.y += hk * u.y;
            acc.z += hk * u.z; acc.w += hk * u.w;
            const float4 v = *(const float4*)(u1 + 32 * c);
            const float hk2 = hr[4 * (s + 4) + c];
            acc2.x += hk2 * v.x; acc2.y += hk2 * v.y;
            acc2.z += hk2 * v.z; acc2.w += hk2 * v.w;
        }
    }
    return add4(acc, acc2);
}

// Runtime dtype probe (see earlier rounds): error prob ~1e-24.
__device__ bool detect_f32(const void* p, int n) {
    const u16* u = (const u16*)p;
    int m = n < 64 ? n : 64;
    bool bad = false;
    for (int k = 0; k < m; k++) {
        float v = bfb2f(u[k]);
        float av = fabsf(v);
        bool sane = (v == v) && (av <= 1e6f) && (av == 0.0f || av >= 1e-8f);
        bad |= !sane;
    }
    return bad;
}

// ---------------- input canonicalization + counter zeroing + dtype flag ------

struct CvtArgs { const void* p[40]; };

__global__ __launch_bounds__(256) void k_convert(CvtArgs a, float* __restrict__ dst,
                                                 int* __restrict__ counters) {
    static constexpr int N[40] = {
        50000,50000,50000,50000,50000,50000,50000,50000,50000,50000,
        2000,6000,6000,
        544,32,1024,32, 160,32,1024,32, 160,32,1024,32,
        2048,1024,32, 1024,1024,32, 1024,1024,32,
        512,16,256,16,16,1};
    if (blockIdx.x == 0 && threadIdx.x < 16) counters[threadIdx.x] = 0;
    int b = blockIdx.x, t = 0, off = 0;
    for (;;) {
        int nb = (N[t] + 255) >> 8;
        if (b < nb) break;
        b -= nb; off += N[t]; ++t;
    }
    const void* src = a.p[t];
    const int n = N[t];
    const bool isf = detect_f32(src, n);
    if (t == 0 && b == 0 && threadIdx.x == 0) counters[16] = isf ? 1 : 0;
    const int i = b * 256 + threadIdx.x;
    if (i < n)
        dst[off + i] = isf ? ((const float*)src)[i] : bfb2f(((const u16*)src)[i]);
}

// ---------------- counting sort by length (DESCENDING: LPT schedule) ---------

__global__ __launch_bounds__(256) void k_hist(const int* __restrict__ length,
                                              int* __restrict__ hist) {
    __shared__ int hc[8];
    const int tid = threadIdx.x;
    if (tid < 8) hc[tid] = 0;
    __syncthreads();
    int p = blockIdx.x * 256 + tid;
    if (p < P_) atomicAdd(&hc[length[p] - 1], 1);
    __syncthreads();
    if (tid < 8 && hc[tid] > 0) atomicAdd(&hist[tid], hc[tid]);
}

__global__ __launch_bounds__(256) void k_scatter(const int* __restrict__ length,
                                                 const int* __restrict__ hist,
                                                 int* __restrict__ cursor,
                                                 int* __restrict__ perm,
                                                 int* __restrict__ inv) {
    __shared__ int cnt[8];
    __shared__ int base[8];
    const int tid = threadIdx.x;
    if (tid < 8) cnt[tid] = 0;
    __syncthreads();
    const int p = blockIdx.x * 256 + tid;
    int b = 0, r = 0;
    if (p < P_) { b = length[p] - 1; r = atomicAdd(&cnt[b], 1); }
    __syncthreads();
    if (tid < 8) {
        int pre = 0;
#pragma unroll
        for (int k = 0; k < 8; k++) pre += (k > tid) ? hist[k] : 0;  // DESC
        base[tid] = pre + (cnt[tid] > 0 ? atomicAdd(&cursor[tid], cnt[tid]) : 0);
    }
    __syncthreads();
    if (p < P_) { const int pos = base[b] + r; perm[pos] = p; inv[p] = pos; }
}

// ---------------- remap into sorted index space ------------------------------

__global__ __launch_bounds__(256) void k_remap(
    const int* __restrict__ perm, const int* __restrict__ inv,
    const int* __restrict__ q2p, const int* __restrict__ l2p,
    const int* __restrict__ length, const int* __restrict__ p2q,
    int* __restrict__ q2ps, int* __restrict__ l2ps, int* __restrict__ lens,
    int* __restrict__ p2qs)
{
    const int blk = blockIdx.x;
    if (blk < RA_) {
        const int idx = blk * 256 + threadIdx.x;
        if (idx >= P_ * 8) return;
        const int j = idx >> 3, t = idx & 7;
        const int p = perm[j];
        q2ps[idx] = q2p[p * 8 + t];
        l2ps[idx] = l2p[p * 8 + t];
        if (t == 0) lens[j] = length[p];
    } else {
        const int e = (blk - RA_) * 256 + threadIdx.x;
        if (e >= NQ_ * P2Q_) return;
        const int2 pr = ((const int2*)p2q)[e];
        ((int2*)p2qs)[e] = make_int2(inv[pr.x], pr.y);
    }
}

// ---------------- path embed: thread/path, LDS-staged weights ----------------

__global__ __launch_bounds__(256) void k_path_embed(
    const float* __restrict__ traffic, const float* __restrict__ packets,
    const float* __restrict__ eq_lambda, const float* __restrict__ avg_pkts_lambda,
    const float* __restrict__ exp_max_factor, const float* __restrict__ pkts_lambda_on,
    const float* __restrict__ avg_t_off, const float* __restrict__ avg_t_on,
    const float* __restrict__ ar_a, const float* __restrict__ sigma,
    const int* __restrict__ model, const int* __restrict__ inv,
    const float* __restrict__ w1, const float* __restrict__ b1,
    const float* __restrict__ w2, const float* __restrict__ b2,
    float* __restrict__ sps)
{
    __shared__ float s_w1[544], s_w2[1024], s_b1[32], s_b2[32];
    const int tid = threadIdx.x;
    for (int idx = tid; idx < 544; idx += 256)  s_w1[idx] = w1[idx];
    for (int idx = tid; idx < 1024; idx += 256) s_w2[idx] = w2[idx];
    if (tid < 32) { s_b1[tid] = b1[tid]; s_b2[tid] = b2[tid]; }
    __syncthreads();

    int p = blockIdx.x * 256 + tid;
    if (p >= P_) return;
    float f[10];
    f[0] = (traffic[p]        - 1385.4059f) * (1.f / 859.8119f);
    f[1] = (packets[p]        - 1.4015f)    * (1.f / 0.8933f);
    f[2] = (eq_lambda[p]      - 1350.9712f) * (1.f / 858.3162f);
    f[3] = (avg_pkts_lambda[p]- 0.9117f)    * (1.f / 0.9724f);
    f[4] = (exp_max_factor[p] - 6.6636f)    * (1.f / 4.7151f);
    f[5] = (pkts_lambda_on[p] - 0.9116f)    * (1.f / 1.6513f);
    f[6] = (avg_t_off[p]      - 1.6649f)    * (1.f / 2.3564f);
    f[7] = (avg_t_on[p]       - 1.6649f)    * (1.f / 2.3564f);
    f[8] = ar_a[p];
    f[9] = sigma[p];
    const int mrow = 2 + model[p];
    float h1[32];
#pragma unroll
    for (int d = 0; d < 32; d++) {
        float a = s_b1[d] + s_w1[mrow * 32 + d];
        a += f[0] * s_w1[0 * 32 + d];
        a += f[1] * s_w1[1 * 32 + d];
#pragma unroll
        for (int j = 0; j < 8; j++) a += f[2 + j] * s_w1[(9 + j) * 32 + d];
        h1[d] = fmaxf(a, 0.f);
    }
    float* dst = sps + (size_t)inv[p] * 32;
#pragma unroll
    for (int d = 0; d < 32; d++) {
        float a = s_b2[d];
#pragma unroll
        for (int k = 0; k < 32; k++) a += h1[k] * s_w2[k * 32 + d];
        dst[d] = fmaxf(a, 0.f);
    }
}

// ---------------- queue embed + zq: thread/queue, LDS-staged weights ---------

__global__ __launch_bounds__(256) void k_queue_embed(
    const float* __restrict__ queue_size, const float* __restrict__ weight,
    const int* __restrict__ priority,
    const float* __restrict__ w1, const float* __restrict__ b1,
    const float* __restrict__ w2, const float* __restrict__ b2,
    const float* __restrict__ prW, const float* __restrict__ prB,
    float* __restrict__ queue_state, float* __restrict__ zq)
{
    __shared__ float s_w1[160], s_w2[1024], s_pw[1024], s_b1[32], s_b2[32], s_pb[32];
    const int tid = threadIdx.x;
    if (tid < 160) s_w1[tid] = w1[tid];
    for (int idx = tid; idx < 1024; idx += 256) {
        s_w2[idx] = w2[idx];
        s_pw[idx] = prW[idx];
    }
    if (tid < 32) { s_b1[tid] = b1[tid]; s_b2[tid] = b2[tid]; s_pb[tid] = prB[tid]; }
    __syncthreads();

    int q = blockIdx.x * 256 + tid;
    if (q >= NQ_) return;
    float f0 = (queue_size[q] - 30259.1055f) * (1.f / 21410.0957f);
    float f4 = weight[q];
    int prow = 1 + priority[q];
    float h1[32];
#pragma unroll
    for (int d = 0; d < 32; d++) {
        float a = s_b1[d] + s_w1[prow * 32 + d]
                + f0 * s_w1[0 * 32 + d] + f4 * s_w1[4 * 32 + d];
        h1[d] = fmaxf(a, 0.f);
    }
    float h2[32];
#pragma unroll
    for (int d = 0; d < 32; d++) {
        float a = s_b2[d];
#pragma unroll
        for (int k = 0; k < 32; k++) a += h1[k] * s_w2[k * 32 + d];
        h2[d] = fmaxf(a, 0.f);
        queue_state[q * 32 + d] = h2[d];
    }
#pragma unroll
    for (int d = 0; d < 32; d++) {
        float a = s_pb[d];
#pragma unroll
        for (int k = 0; k < 32; k++) a += h2[k] * s_pw[k * 32 + d];
        zq[q * 32 + d] = a;
    }
}

// ---------------- link embed + zl: wave/link ---------------------------------

__global__ __launch_bounds__(256) void k_link_embed(
    const float* __restrict__ traffic, const float* __restrict__ capacity,
    const int* __restrict__ policy,
    const int* __restrict__ p2l, const int* __restrict__ p2l_deg,
    const float* __restrict__ w1, const float* __restrict__ b1,
    const float* __restrict__ w2, const float* __restrict__ b2,
    const float* __restrict__ prWl,
    float* __restrict__ link_state, float* __restrict__ zl)
{
    __shared__ float wsh[2272];  // w1[160] b1@160 w2@192 b2@1216 prWl@1248
    __shared__ float h1s[4][32];
    __shared__ float h2s[4][32];
    const int tid = threadIdx.x;
    if (tid < 160) wsh[tid] = w1[tid];
    if (tid < 32)  wsh[160 + tid] = b1[tid];
    for (int idx = tid; idx < 1024; idx += 256) {
        wsh[192 + idx]  = w2[idx];
        wsh[1248 + idx] = prWl[idx];
    }
    if (tid >= 32 && tid < 64) wsh[1216 + tid - 32] = b2[tid - 32];
    __syncthreads();

    const int w = tid >> 6, lane = tid & 63;
    const int l = blockIdx.x * 4 + w;          // grid = 500 exact
    const int deg = p2l_deg[l];
    float s = 0.f;
    if (lane < deg)      s += traffic[p2l[l * 256 + 2 * lane]];
    if (lane + 64 < deg) s += traffic[p2l[l * 256 + 2 * (lane + 64)]];
#pragma unroll
    for (int m = 1; m < 64; m <<= 1) s += __shfl_xor(s, m, 64);
    const float load = s / capacity[l];
    const int prow = 1 + policy[l];
    if (lane < 32) {
        float a = wsh[160 + lane] + wsh[prow * 32 + lane] + load * wsh[lane];
        h1s[w][lane] = fmaxf(a, 0.f);
    }
    __syncthreads();
    if (lane < 32) {
        float a = wsh[1216 + lane];
#pragma unroll
        for (int k = 0; k < 32; k++) a += h1s[w][k] * wsh[192 + k * 32 + lane];
        a = fmaxf(a, 0.f);
        link_state[l * 32 + lane] = a;
        h2s[w][lane] = a;
    }
    __syncthreads();
    if (lane < 32) {
        float a = 0.f;
#pragma unroll
        for (int k = 0; k < 32; k++) a += h2s[w][k] * wsh[1248 + k * 32 + lane];
        zl[l * 32 + lane] = a;
    }
}

// ---------------- path RNN: sorted, len-bounded, weights register-resident ---
// launch_bounds(256,1): allow high VGPR so Ub[32] float4 stays in registers
// (measured occupancy was ~1.4 waves/SIMD anyway -> capping at 2 loses nothing).

__global__ __launch_bounds__(256, 1) void k_path_rnn(
    const int* __restrict__ q2ps, const int* __restrict__ l2ps,
    const int* __restrict__ lens,
    const float* __restrict__ prU,
    const float* __restrict__ zq, const float* __restrict__ zl,
    float* __restrict__ sps, u16* __restrict__ pss)
{
    const int tid = threadIdx.x;
    const int grp = tid >> 3, i = tid & 7;
    const int j = blockIdx.x * 32 + grp;
    if (j >= P_) return;
    const int len = lens[j];

    float4 Ub[32];
#pragma unroll
    for (int s = 0; s < 8; s++) {
        const float* rb = prU + ((i ^ s) * 128 + 4 * i);
#pragma unroll
        for (int c = 0; c < 4; c++)
            Ub[4 * s + c] = *(const float4*)(rb + 32 * c);
    }

    const int4 qi0 = *(const int4*)(q2ps + (size_t)j * 8);
    const int4 qi1 = *(const int4*)(q2ps + (size_t)j * 8 + 4);
    const int4 li0 = *(const int4*)(l2ps + (size_t)j * 8);
    const int4 li1 = *(const int4*)(l2ps + (size_t)j * 8 + 4);
    const int qidx[8] = {qi0.x, qi0.y, qi0.z, qi0.w, qi1.x, qi1.y, qi1.z, qi1.w};
    const int lidx[8] = {li0.x, li0.y, li0.z, li0.w, li1.x, li1.y, li1.z, li1.w};

    float4 own = *(const float4*)(sps + (size_t)j * 32 + 4 * i);
    float hr[32];
    hr_rebuild(hr, own);

    float4 z;
    {
        const float4 a = *(const float4*)(zq + (size_t)qidx[0] * 32 + 4 * i);
        const float4 b = *(const float4*)(zl + (size_t)lidx[0] * 32 + 4 * i);
        z = add4(a, b);
    }

#pragma unroll
    for (int t = 0; t < 8; t++) {
        if (t >= len) break;        // sorted: wave-uniform exit
        float4 accA = z;
        float4 accB = make_float4(0.f, 0.f, 0.f, 0.f);
        if (t + 1 < len) {          // prefetch next z during the matvec
            const float4 a = *(const float4*)(zq + (size_t)qidx[t + 1] * 32 + 4 * i);
            const float4 b = *(const float4*)(zl + (size_t)lidx[t + 1] * 32 + 4 * i);
            z = add4(a, b);
        }
#pragma unroll
        for (int k = 0; k < 16; k++) {     // two 16-deep chains for ILP
            const float hk = hr[k];
            accA.x += hk * Ub[k].x; accA.y += hk * Ub[k].y;
            accA.z += hk * Ub[k].z; accA.w += hk * Ub[k].w;
            const float hk2 = hr[k + 16];
            accB.x += hk2 * Ub[k + 16].x; accB.y += hk2 * Ub[k + 16].y;
            accB.z += hk2 * Ub[k + 16].z; accB.w += hk2 * Ub[k + 16].w;
        }
        own = tanh4(add4(accA, accB));
        uint2 w2;
        w2.x = pk2(own.x, own.y);
        w2.y = pk2(own.z, own.w);
        *(uint2*)(pss + (size_t)j * 256 + t * 32 + 4 * i) = w2;
        if (t + 1 < len) hr_rebuild(hr, own);
    }
    *(float4*)(sps + (size_t)j * 32 + 4 * i) = own;
}

// ---------------- last path RNN + fused readout ------------------------------

__global__ __launch_bounds__(256, 1) void k_rnn_last(
    const int* __restrict__ q2ps, const int* __restrict__ l2ps,
    const int* __restrict__ lens, const int* __restrict__ perm,
    const float* __restrict__ prU,
    const float* __restrict__ zq, const float* __restrict__ zl,
    const float* __restrict__ sps,
    const float* __restrict__ capacity,
    const float* __restrict__ traffic, const float* __restrict__ packets,
    const float* __restrict__ w1, const float* __restrict__ b1,
    const float* __restrict__ w2, const float* __restrict__ b2,
    const float* __restrict__ w3, const float* __restrict__ b3,
    const int* __restrict__ flags, void* __restrict__ out)
{
    __shared__ float wl[817];   // w1[512] b1@512 w2@528 b2@784 w3@800 b3@816
    const int tid = threadIdx.x;
    for (int idx = tid; idx < 512; idx += 256) wl[idx] = w1[idx];
    if (tid < 256) wl[528 + tid] = w2[tid];
    if (tid < 16) {
        wl[512 + tid] = b1[tid];
        wl[784 + tid] = b2[tid];
        wl[800 + tid] = w3[tid];
    }
    if (tid == 0) wl[816] = b3[0];
    __syncthreads();

    const int grp = tid >> 3, i = tid & 7;
    const int j = blockIdx.x * 32 + grp;
    if (j >= P_) return;
    const int len = lens[j];

    float4 Ub[32];
#pragma unroll
    for (int s = 0; s < 8; s++) {
        const float* rb = prU + ((i ^ s) * 128 + 4 * i);
#pragma unroll
        for (int c = 0; c < 4; c++)
            Ub[4 * s + c] = *(const float4*)(rb + 32 * c);
    }

    const int4 qi0 = *(const int4*)(q2ps + (size_t)j * 8);
    const int4 qi1 = *(const int4*)(q2ps + (size_t)j * 8 + 4);
    const int4 li0 = *(const int4*)(l2ps + (size_t)j * 8);
    const int4 li1 = *(const int4*)(l2ps + (size_t)j * 8 + 4);
    const int qidx[8] = {qi0.x, qi0.y, qi0.z, qi0.w, qi1.x, qi1.y, qi1.z, qi1.w};
    const int lidx[8] = {li0.x, li0.y, li0.z, li0.w, li1.x, li1.y, li1.z, li1.w};

    float4 own = *(const float4*)(sps + (size_t)j * 32 + 4 * i);
    float hr[32];
    hr_rebuild(hr, own);

    float4 z;
    {
        const float4 a = *(const float4*)(zq + (size_t)qidx[0] * 32 + 4 * i);
        const float4 b = *(const float4*)(zl + (size_t)lidx[0] * 32 + 4 * i);
        z = add4(a, b);
    }

    float qd = 0.f, ts = 0.f;
#pragma unroll
    for (int t = 0; t < 8; t++) {
        if (t >= len) break;
        float4 accA = z;
        float4 accB = make_float4(0.f, 0.f, 0.f, 0.f);
        if (t + 1 < len) {
            const float4 a = *(const float4*)(zq + (size_t)qidx[t + 1] * 32 + 4 * i);
            const float4 b = *(const float4*)(zl + (size_t)lidx[t + 1] * 32 + 4 * i);
            z = add4(a, b);
        }
#pragma unroll
        for (int k = 0; k < 16; k++) {
            const float hk = hr[k];
            accA.x += hk * Ub[k].x; accA.y += hk * Ub[k].y;
            accA.z += hk * Ub[k].z; accA.w += hk * Ub[k].w;
            const float hk2 = hr[k + 16];
            accB.x += hk2 * Ub[k + 16].x; accB.y += hk2 * Ub[k + 16].y;
            accB.z += hk2 * Ub[k + 16].z; accB.w += hk2 * Ub[k + 16].w;
        }
        own = tanh4(add4(accA, accB));
        hr_rebuild(hr, own);      // needed for both next step and readout

        // readout layer 1 (split chains): lane computes dims 2i, 2i+1 of 16
        float a0 = wl[512 + 2 * i], a1 = wl[512 + 2 * i + 1];
        float b0 = 0.f, b1v = 0.f;
#pragma unroll
        for (int s = 0; s < 4; s++) {
#pragma unroll
            for (int c = 0; c < 4; c++) {
                const int k = 4 * (i ^ s) + c;
                const float2 u = *(const float2*)&wl[k * 16 + 2 * i];
                const float hk = hr[4 * s + c];
                a0 += hk * u.x; a1 += hk * u.y;
                const int k2 = 4 * (i ^ (s + 4)) + c;
                const float2 u2 = *(const float2*)&wl[k2 * 16 + 2 * i];
                const float hk2 = hr[4 * (s + 4) + c];
                b0 += hk2 * u2.x; b1v += hk2 * u2.y;
            }
        }
        a0 = fmaxf(a0 + b0, 0.f); a1 = fmaxf(a1 + b1v, 0.f);
        // replicate h2[16] in butterfly order: h2r[2s+c] = h2[2*(i^s)+c]
        float h2r[16];
        h2r[0] = a0; h2r[1] = a1;
#pragma unroll
        for (int c = 0; c < 2; c++) h2r[2 + c] = __shfl_xor(h2r[c], 1, 64);
#pragma unroll
        for (int c = 0; c < 4; c++) h2r[4 + c] = __shfl_xor(h2r[c], 2, 64);
#pragma unroll
        for (int c = 0; c < 8; c++) h2r[8 + c] = __shfl_xor(h2r[c], 4, 64);
        // layer 2 (split chains)
        float c0 = wl[784 + 2 * i], c1 = wl[784 + 2 * i + 1];
        float d0 = 0.f, d1 = 0.f;
#pragma unroll
        for (int s = 0; s < 4; s++) {
#pragma unroll
            for (int c = 0; c < 2; c++) {
                const int k = 2 * (i ^ s) + c;
                const float2 u = *(const float2*)&wl[528 + k * 16 + 2 * i];
                const float hk = h2r[2 * s + c];
                c0 += hk * u.x; c1 += hk * u.y;
                const int k2 = 2 * (i ^ (s + 4)) + c;
                const float2 u2 = *(const float2*)&wl[528 + k2 * 16 + 2 * i];
                const float hk2 = h2r[2 * (s + 4) + c];
                d0 += hk2 * u2.x; d1 += hk2 * u2.y;
            }
        }
        c0 = fmaxf(c0 + d0, 0.f); c1 = fmaxf(c1 + d1, 0.f);
        float pv = c0 * wl[800 + 2 * i] + c1 * wl[800 + 2 * i + 1];
        pv += __shfl_xor(pv, 1, 8);
        pv += __shfl_xor(pv, 2, 8);
        pv += __shfl_xor(pv, 4, 8);
        const float occv = pv + wl[816];
        const float inv = 1.f / capacity[lidx[t]];
        qd += occv * inv;
        ts += inv;
    }
    if (i == 0) {
        const int p = perm[j];
        const float res = qd + (traffic[p] / packets[p]) * ts;
        if (flags[0]) ((float*)out)[p] = res;
        else          ((bf16*)out)[p] = __float2bfloat16(res);
    }
}

// ---------------- fused queue+link update: 512 threads, 2 links/block --------
// Waves 0..5 update the block's 6 queues IN PARALLEL (full wave/queue each,
// same as the separate kernel); barrier; waves 6..7 run the 2 link GRUs from
// LDS-passed fresh queue states + zl epilogue. Removes 1 launch/iteration.

__global__ __launch_bounds__(512) void k_qlupd(
    const int* __restrict__ p2qs, const int* __restrict__ p2q_deg,
    const int* __restrict__ q2l,
    const float* __restrict__ qrW, const float* __restrict__ qrU,
    const float* __restrict__ qrB,
    const float* __restrict__ lrW, const float* __restrict__ lrU,
    const float* __restrict__ lrB,
    const float* __restrict__ prW, const float* __restrict__ prB,
    const u16* __restrict__ pss, float* __restrict__ queue_state,
    float* __restrict__ link_state,
    float* __restrict__ zq, float* __restrict__ zl)
{
    __shared__ float wl[6 * 1024 + 96 + 192];
    // 0:qrW 1024:qrU 2048:prW0 3072:lrW 4096:lrU 5120:prW1
    // 6144:qrB 6176:prB 6208:lrB 6240:qsh[6][32]
    const int tid = threadIdx.x;
    for (int idx = tid; idx < 1024; idx += 512) {
        wl[idx]        = qrW[idx];
        wl[1024 + idx] = qrU[idx];
        wl[2048 + idx] = prW[idx];
        wl[3072 + idx] = lrW[idx];
        wl[4096 + idx] = lrU[idx];
        wl[5120 + idx] = prW[1024 + idx];
    }
    if (tid < 32) {
        wl[6144 + tid] = qrB[tid];
        wl[6176 + tid] = prB[tid];
        wl[6208 + tid] = lrB[tid];
    }
    __syncthreads();

    const int wv = tid >> 6, lane = tid & 63;
    const int g = lane >> 3, i = lane & 7;
    int offs[8];
#pragma unroll
    for (int s = 0; s < 8; s++) offs[s] = (i ^ s) * 128 + 4 * i;
    float* qsh = wl + 6240;

    if (wv < 6) {
        const int l = blockIdx.x * 2 + (wv / 3);       // grid = NL_/2 exact
        const int q = q2l[l * 3 + (wv % 3)];
        const int deg = p2q_deg[q];
        float4 ps = {0.f, 0.f, 0.f, 0.f};
        for (int j = g; j < deg; j += 8) {
            const int2 pr = ((const int2*)p2qs)[q * 64 + j];
            int pos = pr.y - 1;
            pos = pos < 0 ? 0 : (pos > 7 ? 7 : pos);
            const ushort4 v = *(const ushort4*)(pss + (size_t)pr.x * 256 + pos * 32 + 4 * i);
            ps.x += bfb2f(v.x); ps.y += bfb2f(v.y);
            ps.z += bfb2f(v.z); ps.w += bfb2f(v.w);
        }
#pragma unroll
        for (int m = 8; m < 64; m <<= 1) {
            ps.x += __shfl_xor(ps.x, m, 64);
            ps.y += __shfl_xor(ps.y, m, 64);
            ps.z += __shfl_xor(ps.z, m, 64);
            ps.w += __shfl_xor(ps.w, m, 64);
        }
        const float4 qs = *(const float4*)(queue_state + (size_t)q * 32 + 4 * i);
        float psr[32]; hr_rebuild(psr, ps);
        float qsr[32]; hr_rebuild(qsr, qs);
        float4 accA = *(const float4*)(wl + 6144 + 4 * i);
        accA = matvec32o(psr, wl, offs, accA);
        float4 accB = matvec32o(qsr, wl + 1024, offs, make_float4(0.f, 0.f, 0.f, 0.f));
        const float4 nh = tanh4(add4(accA, accB));
        float nhr[32]; hr_rebuild(nhr, nh);
        float4 zacc = *(const float4*)(wl + 6176 + 4 * i);
        zacc = matvec32o(nhr, wl + 2048, offs, zacc);
        if (g == 0) {
            *(float4*)(queue_state + (size_t)q * 32 + 4 * i) = nh;
            *(float4*)(zq + (size_t)q * 32 + 4 * i) = zacc;
            *(float4*)(qsh + wv * 32 + 4 * i) = nh;
        }
    }
    __syncthreads();
    if (wv >= 6) {
        const int li = wv - 6;
        const int l = blockIdx.x * 2 + li;
        float4 h = *(const float4*)(link_state + (size_t)l * 32 + 4 * i);
        float hhr[32]; hr_rebuild(hhr, h);
#pragma unroll
        for (int c = 0; c < 3; c++) {
            const float4 qg = *(const float4*)(qsh + (li * 3 + c) * 32 + 4 * i);
            float qgr[32]; hr_rebuild(qgr, qg);
            float4 accA = *(const float4*)(wl + 6208 + 4 * i);
            accA = matvec32o(qgr, wl + 3072, offs, accA);
            float4 accB = matvec32o(hhr, wl + 4096, offs, make_float4(0.f, 0.f, 0.f, 0.f));
            h = tanh4(add4(accA, accB));
            hr_rebuild(hhr, h);
        }
        float4 zacc = matvec32o(hhr, wl + 5120, offs, make_float4(0.f, 0.f, 0.f, 0.f));
        if (g == 0) {
            *(float4*)(link_state + (size_t)l * 32 + 4 * i) = h;
            *(float4*)(zl + (size_t)l * 32 + 4 * i) = zacc;
        }
    }
}

// ---------------- launcher ---------------------------------------------------

extern "C" void kernel_launch(void* const* d_in, const int* in_sizes, int n_in,
                              void* d_out, int out_size, void* d_ws, size_t ws_size,
                              hipStream_t stream)
{
    static const int CVT_N[40] = {
        50000,50000,50000,50000,50000,50000,50000,50000,50000,50000,
        2000,6000,6000,
        544,32,1024,32, 160,32,1024,32, 160,32,1024,32,
        2048,1024,32, 1024,1024,32, 1024,1024,32,
        512,16,256,16,16,1};

    const int*  length   = (const int*)d_in[13];
    const int*  model    = (const int*)d_in[14];
    const int*  policy   = (const int*)d_in[15];
    const int*  priority = (const int*)d_in[16];
    const int*  q2p      = (const int*)d_in[17];
    const int*  l2p      = (const int*)d_in[18];
    const int*  p2l      = (const int*)d_in[19];
    const int*  p2l_deg  = (const int*)d_in[20];
    const int*  p2q      = (const int*)d_in[21];
    const int*  p2q_deg  = (const int*)d_in[22];
    const int*  q2l      = (const int*)d_in[23];

    CvtArgs ca;
    for (int i = 0; i < 13; i++) ca.p[i] = d_in[i];
    for (int i = 0; i < 27; i++) ca.p[13 + i] = d_in[24 + i];

    int off[41]; off[0] = 0;
    for (int i = 0; i < 40; i++) off[i + 1] = off[i] + CVT_N[i];
    int nblk = 0;
    for (int i = 0; i < 40; i++) nblk += (CVT_N[i] + 255) / 256;

    float* ws = (float*)d_ws;
    const float* c_traffic    = ws + off[0];
    const float* c_packets    = ws + off[1];
    const float* c_eq_lambda  = ws + off[2];
    const float* c_apl        = ws + off[3];
    const float* c_emf        = ws + off[4];
    const float* c_plo        = ws + off[5];
    const float* c_atoff      = ws + off[6];
    const float* c_aton       = ws + off[7];
    const float* c_ar_a       = ws + off[8];
    const float* c_sigma      = ws + off[9];
    const float* c_capacity   = ws + off[10];
    const float* c_queue_size = ws + off[11];
    const float* c_weight     = ws + off[12];
    const float* c_pe_w1 = ws + off[13]; const float* c_pe_b1 = ws + off[14];
    const float* c_pe_w2 = ws + off[15]; const float* c_pe_b2 = ws + off[16];
    const float* c_le_w1 = ws + off[17]; const float* c_le_b1 = ws + off[18];
    const float* c_le_w2 = ws + off[19]; const float* c_le_b2 = ws + off[20];
    const float* c_qe_w1 = ws + off[21]; const float* c_qe_b1 = ws + off[22];
    const float* c_qe_w2 = ws + off[23]; const float* c_qe_b2 = ws + off[24];
    const float* c_prW = ws + off[25]; const float* c_prU = ws + off[26];
    const float* c_prB = ws + off[27];
    const float* c_qrW = ws + off[28]; const float* c_qrU = ws + off[29];
    const float* c_qrB = ws + off[30];
    const float* c_lrW = ws + off[31]; const float* c_lrU = ws + off[32];
    const float* c_lrB = ws + off[33];
    const float* c_ro_w1 = ws + off[34]; const float* c_ro_b1 = ws + off[35];
    const float* c_ro_w2 = ws + off[36]; const float* c_ro_b2 = ws + off[37];
    const float* c_ro_w3 = ws + off[38]; const float* c_ro_b3 = ws + off[39];

    size_t base = ((size_t)off[40] + 63) & ~(size_t)63;
    float* sps         = ws + base;                          // P*32 (sorted)
    float* queue_state = sps + (size_t)P_ * 32;              // NQ*32
    float* link_state  = queue_state + (size_t)NQ_ * 32;     // NL*32
    float* zq          = link_state + (size_t)NL_ * 32;      // NQ*32
    float* zl          = zq + (size_t)NQ_ * 32;              // NL*32
    u16*   pss         = (u16*)(zl + (size_t)NL_ * 32);      // P*256 bf16 (sorted)
    int*   perm        = (int*)(pss + (size_t)P_ * 256);     // P
    int*   inv         = perm + P_;                          // P
    int*   lens        = inv + P_;                           // P
    int*   q2ps        = lens + P_;                          // P*8
    int*   l2ps        = q2ps + (size_t)P_ * 8;              // P*8
    int*   p2qs        = l2ps + (size_t)P_ * 8;              // NQ*128
    int*   counters    = p2qs + (size_t)NQ_ * 2 * P2Q_;      // hist[8]+cursor[8]+flag
    int*   hist        = counters;
    int*   cursor      = counters + 8;
    int*   flags       = counters + 16;
    // total ws ~43 MB

    k_convert<<<nblk, 256, 0, stream>>>(ca, ws, counters);
    k_hist<<<(P_ + 255) / 256, 256, 0, stream>>>(length, hist);
    k_scatter<<<(P_ + 255) / 256, 256, 0, stream>>>(length, hist, cursor, perm, inv);
    k_remap<<<RA_ + RC_, 256, 0, stream>>>(
        perm, inv, q2p, l2p, length, p2q, q2ps, l2ps, lens, p2qs);

    k_path_embed<<<(P_ + 255) / 256, 256, 0, stream>>>(
        c_traffic, c_packets, c_eq_lambda, c_apl, c_emf, c_plo, c_atoff, c_aton,
        c_ar_a, c_sigma, model, inv, c_pe_w1, c_pe_b1, c_pe_w2, c_pe_b2, sps);
    k_queue_embed<<<(NQ_ + 255) / 256, 256, 0, stream>>>(
        c_queue_size, c_weight, priority, c_qe_w1, c_qe_b1, c_qe_w2, c_qe_b2,
        c_prW, c_prB, queue_state, zq);
    k_link_embed<<<NL_ / 4, 256, 0, stream>>>(
        c_traffic, c_capacity, policy, p2l, p2l_deg,
        c_le_w1, c_le_b1, c_le_w2, c_le_b2, c_prW + 1024, link_state, zl);

    for (int it = 0; it < ITERS_ - 1; ++it) {
        k_path_rnn<<<(P_ + 31) / 32, 256, 0, stream>>>(
            q2ps, l2ps, lens, c_prU, zq, zl, sps, pss);
        k_qlupd<<<NL_ / 2, 512, 0, stream>>>(
            p2qs, p2q_deg, q2l, c_qrW, c_qrU, c_qrB, c_lrW, c_lrU, c_lrB,
            c_prW, c_prB, pss, queue_state, link_state, zq, zl);
    }

    // iteration 7: rnn with fused readout; final qupd/lupd are dead in the ref
    k_rnn_last<<<(P_ + 31) / 32, 256, 0, stream>>>(
        q2ps, l2ps, lens, perm, c_prU, zq, zl, sps,
        c_capacity, c_traffic, c_packets,
        c_ro_w1, c_ro_b1, c_ro_w2, c_ro_b2, c_ro_w3, c_ro_b3,
        flags, d_out);
}

// Round 14
// 664.193 us; speedup vs baseline: 2.3947x; 2.3947x over previous
//
#include <hip/hip_runtime.h>
#include <hip/hip_bf16.h>

#define P_ 50000
#define NL_ 2000
#define NQ_ 6000
#define L_ 8
#define P2L_ 128
#define P2Q_ 64
#define D_ 32
#define ITERS_ 8
#define RA_ 1563  // remap blocks for path-indexed arrays (P_*8/256)
#define RC_ 1500  // remap blocks for p2q pairs (NQ_*P2Q_/256)

typedef __hip_bfloat16 bf16;
typedef unsigned short u16;
typedef unsigned int u32;

__device__ __forceinline__ float bfb2f(u16 u) {
    union { u32 i; float f; } c; c.i = ((u32)u) << 16; return c.f;
}
__device__ __forceinline__ u16 f2bfb(float f) {
    union { bf16 h; u16 u; } c; c.h = __float2bfloat16(f); return c.u;
}
__device__ __forceinline__ u32 pk2(float a, float b) {
    return (u32)f2bfb(a) | ((u32)f2bfb(b) << 16);
}

__device__ __forceinline__ float tanh_fast(float x) {
    return 1.f - 2.f / (__expf(2.f * x) + 1.f);
}
__device__ __forceinline__ float4 tanh4(float4 a) {
    return make_float4(tanh_fast(a.x), tanh_fast(a.y), tanh_fast(a.z), tanh_fast(a.w));
}
__device__ __forceinline__ float4 add4(float4 a, float4 b) {
    return make_float4(a.x + b.x, a.y + b.y, a.z + b.z, a.w + b.w);
}

// butterfly-order replicated state: hr[4s+c] = h[4*(i^s)+c] for this lane's i.
__device__ __forceinline__ void hr_rebuild(float* hr, float4 own) {
    hr[0] = own.x; hr[1] = own.y; hr[2] = own.z; hr[3] = own.w;
#pragma unroll
    for (int c = 0; c < 4; c++)  hr[4 + c]  = __shfl_xor(hr[c], 1, 64);
#pragma unroll
    for (int c = 0; c < 8; c++)  hr[8 + c]  = __shfl_xor(hr[c], 2, 64);
#pragma unroll
    for (int c = 0; c < 16; c++) hr[16 + c] = __shfl_xor(hr[c], 4, 64);
}

// acc += full-h @ W[:,4i..4i+3]; W in LDS at base, offs[s] = (i^s)*128+4i
__device__ __forceinline__ float4 matvec32o(const float* hr, const float* base,
                                            const int* offs, float4 acc) {
#pragma unroll
    for (int s = 0; s < 8; s++) {
        const float* u0 = base + offs[s];
#pragma unroll
        for (int c = 0; c < 4; c++) {
            const float4 u = *(const float4*)(u0 + 32 * c);
            const float hk = hr[4 * s + c];
            acc.x += hk * u.x; acc.y += hk * u.y;
            acc.z += hk * u.z; acc.w += hk * u.w;
        }
    }
    return acc;
}

// Runtime dtype probe (see earlier rounds): error prob ~1e-24.
__device__ bool detect_f32(const void* p, int n) {
    const u16* u = (const u16*)p;
    int m = n < 64 ? n : 64;
    bool bad = false;
    for (int k = 0; k < m; k++) {
        float v = bfb2f(u[k]);
        float av = fabsf(v);
        bool sane = (v == v) && (av <= 1e6f) && (av == 0.0f || av >= 1e-8f);
        bad |= !sane;
    }
    return bad;
}

// ---------------- input canonicalization + counter zeroing + dtype flag ------

struct CvtArgs { const void* p[40]; };

__global__ __launch_bounds__(256) void k_convert(CvtArgs a, float* __restrict__ dst,
                                                 int* __restrict__ counters) {
    static constexpr int N[40] = {
        50000,50000,50000,50000,50000,50000,50000,50000,50000,50000,
        2000,6000,6000,
        544,32,1024,32, 160,32,1024,32, 160,32,1024,32,
        2048,1024,32, 1024,1024,32, 1024,1024,32,
        512,16,256,16,16,1};
    if (blockIdx.x == 0 && threadIdx.x < 16) counters[threadIdx.x] = 0;
    int b = blockIdx.x, t = 0, off = 0;
    for (;;) {
        int nb = (N[t] + 255) >> 8;
        if (b < nb) break;
        b -= nb; off += N[t]; ++t;
    }
    const void* src = a.p[t];
    const int n = N[t];
    const bool isf = detect_f32(src, n);
    if (t == 0 && b == 0 && threadIdx.x == 0) counters[16] = isf ? 1 : 0;
    const int i = b * 256 + threadIdx.x;
    if (i < n)
        dst[off + i] = isf ? ((const float*)src)[i] : bfb2f(((const u16*)src)[i]);
}

// ---------------- counting sort by length (DESCENDING: LPT schedule) ---------

__global__ __launch_bounds__(256) void k_hist(const int* __restrict__ length,
                                              int* __restrict__ hist) {
    __shared__ int hc[8];
    const int tid = threadIdx.x;
    if (tid < 8) hc[tid] = 0;
    __syncthreads();
    int p = blockIdx.x * 256 + tid;
    if (p < P_) atomicAdd(&hc[length[p] - 1], 1);
    __syncthreads();
    if (tid < 8 && hc[tid] > 0) atomicAdd(&hist[tid], hc[tid]);
}

__global__ __launch_bounds__(256) void k_scatter(const int* __restrict__ length,
                                                 const int* __restrict__ hist,
                                                 int* __restrict__ cursor,
                                                 int* __restrict__ perm,
                                                 int* __restrict__ inv) {
    __shared__ int cnt[8];
    __shared__ int base[8];
    const int tid = threadIdx.x;
    if (tid < 8) cnt[tid] = 0;
    __syncthreads();
    const int p = blockIdx.x * 256 + tid;
    int b = 0, r = 0;
    if (p < P_) { b = length[p] - 1; r = atomicAdd(&cnt[b], 1); }
    __syncthreads();
    if (tid < 8) {
        int pre = 0;
#pragma unroll
        for (int k = 0; k < 8; k++) pre += (k > tid) ? hist[k] : 0;  // DESC
        base[tid] = pre + (cnt[tid] > 0 ? atomicAdd(&cursor[tid], cnt[tid]) : 0);
    }
    __syncthreads();
    if (p < P_) { const int pos = base[b] + r; perm[pos] = p; inv[p] = pos; }
}

// ---------------- remap into sorted index space ------------------------------

__global__ __launch_bounds__(256) void k_remap(
    const int* __restrict__ perm, const int* __restrict__ inv,
    const int* __restrict__ q2p, const int* __restrict__ l2p,
    const int* __restrict__ length, const int* __restrict__ p2q,
    int* __restrict__ q2ps, int* __restrict__ l2ps, int* __restrict__ lens,
    int* __restrict__ p2qs)
{
    const int blk = blockIdx.x;
    if (blk < RA_) {
        const int idx = blk * 256 + threadIdx.x;
        if (idx >= P_ * 8) return;
        const int j = idx >> 3, t = idx & 7;
        const int p = perm[j];
        q2ps[idx] = q2p[p * 8 + t];
        l2ps[idx] = l2p[p * 8 + t];
        if (t == 0) lens[j] = length[p];
    } else {
        const int e = (blk - RA_) * 256 + threadIdx.x;
        if (e >= NQ_ * P2Q_) return;
        const int2 pr = ((const int2*)p2q)[e];
        ((int2*)p2qs)[e] = make_int2(inv[pr.x], pr.y);
    }
}

// ---------------- path embed: thread/path, LDS-staged weights ----------------

__global__ __launch_bounds__(256) void k_path_embed(
    const float* __restrict__ traffic, const float* __restrict__ packets,
    const float* __restrict__ eq_lambda, const float* __restrict__ avg_pkts_lambda,
    const float* __restrict__ exp_max_factor, const float* __restrict__ pkts_lambda_on,
    const float* __restrict__ avg_t_off, const float* __restrict__ avg_t_on,
    const float* __restrict__ ar_a, const float* __restrict__ sigma,
    const int* __restrict__ model, const int* __restrict__ inv,
    const float* __restrict__ w1, const float* __restrict__ b1,
    const float* __restrict__ w2, const float* __restrict__ b2,
    float* __restrict__ sps)
{
    __shared__ float s_w1[544], s_w2[1024], s_b1[32], s_b2[32];
    const int tid = threadIdx.x;
    for (int idx = tid; idx < 544; idx += 256)  s_w1[idx] = w1[idx];
    for (int idx = tid; idx < 1024; idx += 256) s_w2[idx] = w2[idx];
    if (tid < 32) { s_b1[tid] = b1[tid]; s_b2[tid] = b2[tid]; }
    __syncthreads();

    int p = blockIdx.x * 256 + tid;
    if (p >= P_) return;
    float f[10];
    f[0] = (traffic[p]        - 1385.4059f) * (1.f / 859.8119f);
    f[1] = (packets[p]        - 1.4015f)    * (1.f / 0.8933f);
    f[2] = (eq_lambda[p]      - 1350.9712f) * (1.f / 858.3162f);
    f[3] = (avg_pkts_lambda[p]- 0.9117f)    * (1.f / 0.9724f);
    f[4] = (exp_max_factor[p] - 6.6636f)    * (1.f / 4.7151f);
    f[5] = (pkts_lambda_on[p] - 0.9116f)    * (1.f / 1.6513f);
    f[6] = (avg_t_off[p]      - 1.6649f)    * (1.f / 2.3564f);
    f[7] = (avg_t_on[p]       - 1.6649f)    * (1.f / 2.3564f);
    f[8] = ar_a[p];
    f[9] = sigma[p];
    const int mrow = 2 + model[p];
    float h1[32];
#pragma unroll
    for (int d = 0; d < 32; d++) {
        float a = s_b1[d] + s_w1[mrow * 32 + d];
        a += f[0] * s_w1[0 * 32 + d];
        a += f[1] * s_w1[1 * 32 + d];
#pragma unroll
        for (int j = 0; j < 8; j++) a += f[2 + j] * s_w1[(9 + j) * 32 + d];
        h1[d] = fmaxf(a, 0.f);
    }
    float* dst = sps + (size_t)inv[p] * 32;
#pragma unroll
    for (int d = 0; d < 32; d++) {
        float a = s_b2[d];
#pragma unroll
        for (int k = 0; k < 32; k++) a += h1[k] * s_w2[k * 32 + d];
        dst[d] = fmaxf(a, 0.f);
    }
}

// ---------------- queue embed + zq: thread/queue, LDS-staged weights ---------

__global__ __launch_bounds__(256) void k_queue_embed(
    const float* __restrict__ queue_size, const float* __restrict__ weight,
    const int* __restrict__ priority,
    const float* __restrict__ w1, const float* __restrict__ b1,
    const float* __restrict__ w2, const float* __restrict__ b2,
    const float* __restrict__ prW, const float* __restrict__ prB,
    float* __restrict__ queue_state, float* __restrict__ zq)
{
    __shared__ float s_w1[160], s_w2[1024], s_pw[1024], s_b1[32], s_b2[32], s_pb[32];
    const int tid = threadIdx.x;
    if (tid < 160) s_w1[tid] = w1[tid];
    for (int idx = tid; idx < 1024; idx += 256) {
        s_w2[idx] = w2[idx];
        s_pw[idx] = prW[idx];
    }
    if (tid < 32) { s_b1[tid] = b1[tid]; s_b2[tid] = b2[tid]; s_pb[tid] = prB[tid]; }
    __syncthreads();

    int q = blockIdx.x * 256 + tid;
    if (q >= NQ_) return;
    float f0 = (queue_size[q] - 30259.1055f) * (1.f / 21410.0957f);
    float f4 = weight[q];
    int prow = 1 + priority[q];
    float h1[32];
#pragma unroll
    for (int d = 0; d < 32; d++) {
        float a = s_b1[d] + s_w1[prow * 32 + d]
                + f0 * s_w1[0 * 32 + d] + f4 * s_w1[4 * 32 + d];
        h1[d] = fmaxf(a, 0.f);
    }
    float h2[32];
#pragma unroll
    for (int d = 0; d < 32; d++) {
        float a = s_b2[d];
#pragma unroll
        for (int k = 0; k < 32; k++) a += h1[k] * s_w2[k * 32 + d];
        h2[d] = fmaxf(a, 0.f);
        queue_state[q * 32 + d] = h2[d];
    }
#pragma unroll
    for (int d = 0; d < 32; d++) {
        float a = s_pb[d];
#pragma unroll
        for (int k = 0; k < 32; k++) a += h2[k] * s_pw[k * 32 + d];
        zq[q * 32 + d] = a;
    }
}

// ---------------- link embed + zl: wave/link ---------------------------------

__global__ __launch_bounds__(256) void k_link_embed(
    const float* __restrict__ traffic, const float* __restrict__ capacity,
    const int* __restrict__ policy,
    const int* __restrict__ p2l, const int* __restrict__ p2l_deg,
    const float* __restrict__ w1, const float* __restrict__ b1,
    const float* __restrict__ w2, const float* __restrict__ b2,
    const float* __restrict__ prWl,
    float* __restrict__ link_state, float* __restrict__ zl)
{
    __shared__ float wsh[2272];  // w1[160] b1@160 w2@192 b2@1216 prWl@1248
    __shared__ float h1s[4][32];
    __shared__ float h2s[4][32];
    const int tid = threadIdx.x;
    if (tid < 160) wsh[tid] = w1[tid];
    if (tid < 32)  wsh[160 + tid] = b1[tid];
    for (int idx = tid; idx < 1024; idx += 256) {
        wsh[192 + idx]  = w2[idx];
        wsh[1248 + idx] = prWl[idx];
    }
    if (tid >= 32 && tid < 64) wsh[1216 + tid - 32] = b2[tid - 32];
    __syncthreads();

    const int w = tid >> 6, lane = tid & 63;
    const int l = blockIdx.x * 4 + w;          // grid = 500 exact
    const int deg = p2l_deg[l];
    float s = 0.f;
    if (lane < deg)      s += traffic[p2l[l * 256 + 2 * lane]];
    if (lane + 64 < deg) s += traffic[p2l[l * 256 + 2 * (lane + 64)]];
#pragma unroll
    for (int m = 1; m < 64; m <<= 1) s += __shfl_xor(s, m, 64);
    const float load = s / capacity[l];
    const int prow = 1 + policy[l];
    if (lane < 32) {
        float a = wsh[160 + lane] + wsh[prow * 32 + lane] + load * wsh[lane];
        h1s[w][lane] = fmaxf(a, 0.f);
    }
    __syncthreads();
    if (lane < 32) {
        float a = wsh[1216 + lane];
#pragma unroll
        for (int k = 0; k < 32; k++) a += h1s[w][k] * wsh[192 + k * 32 + lane];
        a = fmaxf(a, 0.f);
        link_state[l * 32 + lane] = a;
        h2s[w][lane] = a;
    }
    __syncthreads();
    if (lane < 32) {
        float a = 0.f;
#pragma unroll
        for (int k = 0; k < 32; k++) a += h2s[w][k] * wsh[1248 + k * 32 + lane];
        zl[l * 32 + lane] = a;
    }
}

// ---------------- path RNN: sorted, len-bounded, weights register-resident ---

__global__ __launch_bounds__(256, 1) void k_path_rnn(
    const int* __restrict__ q2ps, const int* __restrict__ l2ps,
    const int* __restrict__ lens,
    const float* __restrict__ prU,
    const float* __restrict__ zq, const float* __restrict__ zl,
    float* __restrict__ sps, u16* __restrict__ pss)
{
    const int tid = threadIdx.x;
    const int grp = tid >> 3, i = tid & 7;
    const int j = blockIdx.x * 32 + grp;
    if (j >= P_) return;
    const int len = lens[j];

    float4 Ub[32];
#pragma unroll
    for (int s = 0; s < 8; s++) {
        const float* rb = prU + ((i ^ s) * 128 + 4 * i);
#pragma unroll
        for (int c = 0; c < 4; c++)
            Ub[4 * s + c] = *(const float4*)(rb + 32 * c);
    }

    const int4 qi0 = *(const int4*)(q2ps + (size_t)j * 8);
    const int4 qi1 = *(const int4*)(q2ps + (size_t)j * 8 + 4);
    const int4 li0 = *(const int4*)(l2ps + (size_t)j * 8);
    const int4 li1 = *(const int4*)(l2ps + (size_t)j * 8 + 4);
    const int qidx[8] = {qi0.x, qi0.y, qi0.z, qi0.w, qi1.x, qi1.y, qi1.z, qi1.w};
    const int lidx[8] = {li0.x, li0.y, li0.z, li0.w, li1.x, li1.y, li1.z, li1.w};

    float4 own = *(const float4*)(sps + (size_t)j * 32 + 4 * i);
    float hr[32];
    hr_rebuild(hr, own);

    float4 z;
    {
        const float4 a = *(const float4*)(zq + (size_t)qidx[0] * 32 + 4 * i);
        const float4 b = *(const float4*)(zl + (size_t)lidx[0] * 32 + 4 * i);
        z = add4(a, b);
    }

#pragma unroll
    for (int t = 0; t < 8; t++) {
        if (t >= len) break;        // sorted: wave-uniform exit
        float4 accA = z;
        float4 accB = make_float4(0.f, 0.f, 0.f, 0.f);
        if (t + 1 < len) {          // prefetch next z during the matvec
            const float4 a = *(const float4*)(zq + (size_t)qidx[t + 1] * 32 + 4 * i);
            const float4 b = *(const float4*)(zl + (size_t)lidx[t + 1] * 32 + 4 * i);
            z = add4(a, b);
        }
#pragma unroll
        for (int k = 0; k < 16; k++) {     // two 16-deep chains for ILP
            const float hk = hr[k];
            accA.x += hk * Ub[k].x; accA.y += hk * Ub[k].y;
            accA.z += hk * Ub[k].z; accA.w += hk * Ub[k].w;
            const float hk2 = hr[k + 16];
            accB.x += hk2 * Ub[k + 16].x; accB.y += hk2 * Ub[k + 16].y;
            accB.z += hk2 * Ub[k + 16].z; accB.w += hk2 * Ub[k + 16].w;
        }
        own = tanh4(add4(accA, accB));
        uint2 w2;
        w2.x = pk2(own.x, own.y);
        w2.y = pk2(own.z, own.w);
        *(uint2*)(pss + (size_t)j * 256 + t * 32 + 4 * i) = w2;
        if (t + 1 < len) hr_rebuild(hr, own);
    }
    *(float4*)(sps + (size_t)j * 32 + 4 * i) = own;
}

// ---------------- last path RNN + fused readout ------------------------------

__global__ __launch_bounds__(256, 1) void k_rnn_last(
    const int* __restrict__ q2ps, const int* __restrict__ l2ps,
    const int* __restrict__ lens, const int* __restrict__ perm,
    const float* __restrict__ prU,
    const float* __restrict__ zq, const float* __restrict__ zl,
    const float* __restrict__ sps,
    const float* __restrict__ capacity,
    const float* __restrict__ traffic, const float* __restrict__ packets,
    const float* __restrict__ w1, const float* __restrict__ b1,
    const float* __restrict__ w2, const float* __restrict__ b2,
    const float* __restrict__ w3, const float* __restrict__ b3,
    const int* __restrict__ flags, void* __restrict__ out)
{
    __shared__ float wl[817];   // w1[512] b1@512 w2@528 b2@784 w3@800 b3@816
    const int tid = threadIdx.x;
    for (int idx = tid; idx < 512; idx += 256) wl[idx] = w1[idx];
    if (tid < 256) wl[528 + tid] = w2[tid];
    if (tid < 16) {
        wl[512 + tid] = b1[tid];
        wl[784 + tid] = b2[tid];
        wl[800 + tid] = w3[tid];
    }
    if (tid == 0) wl[816] = b3[0];
    __syncthreads();

    const int grp = tid >> 3, i = tid & 7;
    const int j = blockIdx.x * 32 + grp;
    if (j >= P_) return;
    const int len = lens[j];

    float4 Ub[32];
#pragma unroll
    for (int s = 0; s < 8; s++) {
        const float* rb = prU + ((i ^ s) * 128 + 4 * i);
#pragma unroll
        for (int c = 0; c < 4; c++)
            Ub[4 * s + c] = *(const float4*)(rb + 32 * c);
    }

    const int4 qi0 = *(const int4*)(q2ps + (size_t)j * 8);
    const int4 qi1 = *(const int4*)(q2ps + (size_t)j * 8 + 4);
    const int4 li0 = *(const int4*)(l2ps + (size_t)j * 8);
    const int4 li1 = *(const int4*)(l2ps + (size_t)j * 8 + 4);
    const int qidx[8] = {qi0.x, qi0.y, qi0.z, qi0.w, qi1.x, qi1.y, qi1.z, qi1.w};
    const int lidx[8] = {li0.x, li0.y, li0.z, li0.w, li1.x, li1.y, li1.z, li1.w};

    float4 own = *(const float4*)(sps + (size_t)j * 32 + 4 * i);
    float hr[32];
    hr_rebuild(hr, own);

    float4 z;
    {
        const float4 a = *(const float4*)(zq + (size_t)qidx[0] * 32 + 4 * i);
        const float4 b = *(const float4*)(zl + (size_t)lidx[0] * 32 + 4 * i);
        z = add4(a, b);
    }

    float qd = 0.f, ts = 0.f;
#pragma unroll
    for (int t = 0; t < 8; t++) {
        if (t >= len) break;
        float4 accA = z;
        float4 accB = make_float4(0.f, 0.f, 0.f, 0.f);
        if (t + 1 < len) {
            const float4 a = *(const float4*)(zq + (size_t)qidx[t + 1] * 32 + 4 * i);
            const float4 b = *(const float4*)(zl + (size_t)lidx[t + 1] * 32 + 4 * i);
            z = add4(a, b);
        }
#pragma unroll
        for (int k = 0; k < 16; k++) {
            const float hk = hr[k];
            accA.x += hk * Ub[k].x; accA.y += hk * Ub[k].y;
            accA.z += hk * Ub[k].z; accA.w += hk * Ub[k].w;
            const float hk2 = hr[k + 16];
            accB.x += hk2 * Ub[k + 16].x; accB.y += hk2 * Ub[k + 16].y;
            accB.z += hk2 * Ub[k + 16].z; accB.w += hk2 * Ub[k + 16].w;
        }
        own = tanh4(add4(accA, accB));
        hr_rebuild(hr, own);      // needed for both next step and readout

        // readout layer 1 (split chains): lane computes dims 2i, 2i+1 of 16
        float a0 = wl[512 + 2 * i], a1 = wl[512 + 2 * i + 1];
        float b0 = 0.f, b1v = 0.f;
#pragma unroll
        for (int s = 0; s < 4; s++) {
#pragma unroll
            for (int c = 0; c < 4; c++) {
                const int k = 4 * (i ^ s) + c;
                const float2 u = *(const float2*)&wl[k * 16 + 2 * i];
                const float hk = hr[4 * s + c];
                a0 += hk * u.x; a1 += hk * u.y;
                const int k2 = 4 * (i ^ (s + 4)) + c;
                const float2 u2 = *(const float2*)&wl[k2 * 16 + 2 * i];
                const float hk2 = hr[4 * (s + 4) + c];
                b0 += hk2 * u2.x; b1v += hk2 * u2.y;
            }
        }
        a0 = fmaxf(a0 + b0, 0.f); a1 = fmaxf(a1 + b1v, 0.f);
        // replicate h2[16] in butterfly order: h2r[2s+c] = h2[2*(i^s)+c]
        float h2r[16];
        h2r[0] = a0; h2r[1] = a1;
#pragma unroll
        for (int c = 0; c < 2; c++) h2r[2 + c] = __shfl_xor(h2r[c], 1, 64);
#pragma unroll
        for (int c = 0; c < 4; c++) h2r[4 + c] = __shfl_xor(h2r[c], 2, 64);
#pragma unroll
        for (int c = 0; c < 8; c++) h2r[8 + c] = __shfl_xor(h2r[c], 4, 64);
        // layer 2 (split chains)
        float c0 = wl[784 + 2 * i], c1 = wl[784 + 2 * i + 1];
        float d0 = 0.f, d1 = 0.f;
#pragma unroll
        for (int s = 0; s < 4; s++) {
#pragma unroll
            for (int c = 0; c < 2; c++) {
                const int k = 2 * (i ^ s) + c;
                const float2 u = *(const float2*)&wl[528 + k * 16 + 2 * i];
                const float hk = h2r[2 * s + c];
                c0 += hk * u.x; c1 += hk * u.y;
                const int k2 = 2 * (i ^ (s + 4)) + c;
                const float2 u2 = *(const float2*)&wl[528 + k2 * 16 + 2 * i];
                const float hk2 = h2r[2 * (s + 4) + c];
                d0 += hk2 * u2.x; d1 += hk2 * u2.y;
            }
        }
        c0 = fmaxf(c0 + d0, 0.f); c1 = fmaxf(c1 + d1, 0.f);
        float pv = c0 * wl[800 + 2 * i] + c1 * wl[800 + 2 * i + 1];
        pv += __shfl_xor(pv, 1, 8);
        pv += __shfl_xor(pv, 2, 8);
        pv += __shfl_xor(pv, 4, 8);
        const float occv = pv + wl[816];
        const float inv = 1.f / capacity[lidx[t]];
        qd += occv * inv;
        ts += inv;
    }
    if (i == 0) {
        const int p = perm[j];
        const float res = qd + (traffic[p] / packets[p]) * ts;
        if (flags[0]) ((float*)out)[p] = res;
        else          ((bf16*)out)[p] = __float2bfloat16(res);
    }
}

// ---------------- queue update: wave/queue, fused zq (iters 0..6) ------------

__global__ __launch_bounds__(256) void k_queue_update(
    const int* __restrict__ p2qs, const int* __restrict__ p2q_deg,
    const float* __restrict__ qrW, const float* __restrict__ qrU,
    const float* __restrict__ qrB,
    const float* __restrict__ prWq, const float* __restrict__ prB,
    const u16* __restrict__ pss, float* __restrict__ queue_state,
    float* __restrict__ zq)
{
    __shared__ float wl[3 * 1024 + 64]; // qrW@0 qrU@1024 prWq@2048 qrB@3072 prB@3104
    const int tid = threadIdx.x;
#pragma unroll
    for (int jj = 0; jj < 4; jj++) {
        wl[tid + 256 * jj]        = qrW[tid + 256 * jj];
        wl[1024 + tid + 256 * jj] = qrU[tid + 256 * jj];
        wl[2048 + tid + 256 * jj] = prWq[tid + 256 * jj];
    }
    if (tid < 32) { wl[3072 + tid] = qrB[tid]; wl[3104 + tid] = prB[tid]; }
    __syncthreads();

    const int w = tid >> 6, lane = tid & 63;
    const int g = lane >> 3, i = lane & 7;
    const int q = blockIdx.x * 4 + w;          // grid = 1500 exact
    const int deg = p2q_deg[q];

    int offs[8];
#pragma unroll
    for (int s = 0; s < 8; s++) offs[s] = (i ^ s) * 128 + 4 * i;

    float4 ps = {0.f, 0.f, 0.f, 0.f};
    for (int j = g; j < deg; j += 8) {
        const int2 pr = ((const int2*)p2qs)[q * 64 + j];
        int pos = pr.y - 1;
        pos = pos < 0 ? 0 : (pos > 7 ? 7 : pos);
        const ushort4 v = *(const ushort4*)(pss + (size_t)pr.x * 256 + pos * 32 + 4 * i);
        ps.x += bfb2f(v.x); ps.y += bfb2f(v.y);
        ps.z += bfb2f(v.z); ps.w += bfb2f(v.w);
    }
#pragma unroll
    for (int m = 8; m < 64; m <<= 1) {
        ps.x += __shfl_xor(ps.x, m, 64);
        ps.y += __shfl_xor(ps.y, m, 64);
        ps.z += __shfl_xor(ps.z, m, 64);
        ps.w += __shfl_xor(ps.w, m, 64);
    }
    const float4 qs = *(const float4*)(queue_state + (size_t)q * 32 + 4 * i);

    float psr[32]; hr_rebuild(psr, ps);
    float qsr[32]; hr_rebuild(qsr, qs);
    float4 acc = *(const float4*)(wl + 3072 + 4 * i);
    acc = matvec32o(psr, wl, offs, acc);
    acc = matvec32o(qsr, wl + 1024, offs, acc);
    const float4 nh = tanh4(acc);

    float nhr[32]; hr_rebuild(nhr, nh);
    float4 zacc = *(const float4*)(wl + 3104 + 4 * i);
    zacc = matvec32o(nhr, wl + 2048, offs, zacc);

    if (g == 0) {
        *(float4*)(queue_state + (size_t)q * 32 + 4 * i) = nh;
        *(float4*)(zq + (size_t)q * 32 + 4 * i) = zacc;
    }
}

// ---------------- link update: wave/link, fused zl (iters 0..6) --------------

__global__ __launch_bounds__(256) void k_link_update(
    const int* __restrict__ q2l,
    const float* __restrict__ lrW, const float* __restrict__ lrU,
    const float* __restrict__ lrB,
    const float* __restrict__ prWl,
    const float* __restrict__ queue_state, float* __restrict__ link_state,
    float* __restrict__ zl)
{
    __shared__ float wl[3 * 1024 + 32]; // lrW@0 lrU@1024 prWl@2048 lrB@3072
    const int tid = threadIdx.x;
#pragma unroll
    for (int jj = 0; jj < 4; jj++) {
        wl[tid + 256 * jj]        = lrW[tid + 256 * jj];
        wl[1024 + tid + 256 * jj] = lrU[tid + 256 * jj];
        wl[2048 + tid + 256 * jj] = prWl[tid + 256 * jj];
    }
    if (tid < 32) wl[3072 + tid] = lrB[tid];
    __syncthreads();

    const int w = tid >> 6, lane = tid & 63;
    const int i = lane & 7, g = lane >> 3;
    const int l = blockIdx.x * 4 + w;          // grid = 500 exact

    int offs[8];
#pragma unroll
    for (int s = 0; s < 8; s++) offs[s] = (i ^ s) * 128 + 4 * i;

    float4 h = *(const float4*)(link_state + (size_t)l * 32 + 4 * i);
    float hhr[32]; hr_rebuild(hhr, h);

#pragma unroll
    for (int t = 0; t < 3; t++) {
        const int qq = q2l[l * 3 + t];
        const float4 qg = *(const float4*)(queue_state + (size_t)qq * 32 + 4 * i);
        float qgr[32]; hr_rebuild(qgr, qg);
        float4 acc = *(const float4*)(wl + 3072 + 4 * i);
        acc = matvec32o(qgr, wl, offs, acc);
        acc = matvec32o(hhr, wl + 1024, offs, acc);
        h = tanh4(acc);
        hr_rebuild(hhr, h);
    }
    float4 zacc = make_float4(0.f, 0.f, 0.f, 0.f);
    zacc = matvec32o(hhr, wl + 2048, offs, zacc);
    if (g == 0) {
        *(float4*)(link_state + (size_t)l * 32 + 4 * i) = h;
        *(float4*)(zl + (size_t)l * 32 + 4 * i) = zacc;
    }
}

// ---------------- launcher ---------------------------------------------------

extern "C" void kernel_launch(void* const* d_in, const int* in_sizes, int n_in,
                              void* d_out, int out_size, void* d_ws, size_t ws_size,
                              hipStream_t stream)
{
    static const int CVT_N[40] = {
        50000,50000,50000,50000,50000,50000,50000,50000,50000,50000,
        2000,6000,6000,
        544,32,1024,32, 160,32,1024,32, 160,32,1024,32,
        2048,1024,32, 1024,1024,32, 1024,1024,32,
        512,16,256,16,16,1};

    const int*  length   = (const int*)d_in[13];
    const int*  model    = (const int*)d_in[14];
    const int*  policy   = (const int*)d_in[15];
    const int*  priority = (const int*)d_in[16];
    const int*  q2p      = (const int*)d_in[17];
    const int*  l2p      = (const int*)d_in[18];
    const int*  p2l      = (const int*)d_in[19];
    const int*  p2l_deg  = (const int*)d_in[20];
    const int*  p2q      = (const int*)d_in[21];
    const int*  p2q_deg  = (const int*)d_in[22];
    const int*  q2l      = (const int*)d_in[23];

    CvtArgs ca;
    for (int i = 0; i < 13; i++) ca.p[i] = d_in[i];
    for (int i = 0; i < 27; i++) ca.p[13 + i] = d_in[24 + i];

    int off[41]; off[0] = 0;
    for (int i = 0; i < 40; i++) off[i + 1] = off[i] + CVT_N[i];
    int nblk = 0;
    for (int i = 0; i < 40; i++) nblk += (CVT_N[i] + 255) / 256;

    float* ws = (float*)d_ws;
    const float* c_traffic    = ws + off[0];
    const float* c_packets    = ws + off[1];
    const float* c_eq_lambda  = ws + off[2];
    const float* c_apl        = ws + off[3];
    const float* c_emf        = ws + off[4];
    const float* c_plo        = ws + off[5];
    const float* c_atoff      = ws + off[6];
    const float* c_aton       = ws + off[7];
    const float* c_ar_a       = ws + off[8];
    const float* c_sigma      = ws + off[9];
    const float* c_capacity   = ws + off[10];
    const float* c_queue_size = ws + off[11];
    const float* c_weight     = ws + off[12];
    const float* c_pe_w1 = ws + off[13]; const float* c_pe_b1 = ws + off[14];
    const float* c_pe_w2 = ws + off[15]; const float* c_pe_b2 = ws + off[16];
    const float* c_le_w1 = ws + off[17]; const float* c_le_b1 = ws + off[18];
    const float* c_le_w2 = ws + off[19]; const float* c_le_b2 = ws + off[20];
    const float* c_qe_w1 = ws + off[21]; const float* c_qe_b1 = ws + off[22];
    const float* c_qe_w2 = ws + off[23]; const float* c_qe_b2 = ws + off[24];
    const float* c_prW = ws + off[25]; const float* c_prU = ws + off[26];
    const float* c_prB = ws + off[27];
    const float* c_qrW = ws + off[28]; const float* c_qrU = ws + off[29];
    const float* c_qrB = ws + off[30];
    const float* c_lrW = ws + off[31]; const float* c_lrU = ws + off[32];
    const float* c_lrB = ws + off[33];
    const float* c_ro_w1 = ws + off[34]; const float* c_ro_b1 = ws + off[35];
    const float* c_ro_w2 = ws + off[36]; const float* c_ro_b2 = ws + off[37];
    const float* c_ro_w3 = ws + off[38]; const float* c_ro_b3 = ws + off[39];

    size_t base = ((size_t)off[40] + 63) & ~(size_t)63;
    float* sps         = ws + base;                          // P*32 (sorted)
    float* queue_state = sps + (size_t)P_ * 32;              // NQ*32
    float* link_state  = queue_state + (size_t)NQ_ * 32;     // NL*32
    float* zq          = link_state + (size_t)NL_ * 32;      // NQ*32
    float* zl          = zq + (size_t)NQ_ * 32;              // NL*32
    u16*   pss         = (u16*)(zl + (size_t)NL_ * 32);      // P*256 bf16 (sorted)
    int*   perm        = (int*)(pss + (size_t)P_ * 256);     // P
    int*   inv         = perm + P_;                          // P
    int*   lens        = inv + P_;                           // P
    int*   q2ps        = lens + P_;                          // P*8
    int*   l2ps        = q2ps + (size_t)P_ * 8;              // P*8
    int*   p2qs        = l2ps + (size_t)P_ * 8;              // NQ*128
    int*   counters    = p2qs + (size_t)NQ_ * 2 * P2Q_;      // hist[8]+cursor[8]+flag
    int*   hist        = counters;
    int*   cursor      = counters + 8;
    int*   flags       = counters + 16;
    // total ws ~43 MB

    k_convert<<<nblk, 256, 0, stream>>>(ca, ws, counters);
    k_hist<<<(P_ + 255) / 256, 256, 0, stream>>>(length, hist);
    k_scatter<<<(P_ + 255) / 256, 256, 0, stream>>>(length, hist, cursor, perm, inv);
    k_remap<<<RA_ + RC_, 256, 0, stream>>>(
        perm, inv, q2p, l2p, length, p2q, q2ps, l2ps, lens, p2qs);

    k_path_embed<<<(P_ + 255) / 256, 256, 0, stream>>>(
        c_traffic, c_packets, c_eq_lambda, c_apl, c_emf, c_plo, c_atoff, c_aton,
        c_ar_a, c_sigma, model, inv, c_pe_w1, c_pe_b1, c_pe_w2, c_pe_b2, sps);
    k_queue_embed<<<(NQ_ + 255) / 256, 256, 0, stream>>>(
        c_queue_size, c_weight, priority, c_qe_w1, c_qe_b1, c_qe_w2, c_qe_b2,
        c_prW, c_prB, queue_state, zq);
    k_link_embed<<<NL_ / 4, 256, 0, stream>>>(
        c_traffic, c_capacity, policy, p2l, p2l_deg,
        c_le_w1, c_le_b1, c_le_w2, c_le_b2, c_prW + 1024, link_state, zl);

    for (int it = 0; it < ITERS_ - 1; ++it) {
        k_path_rnn<<<(P_ + 31) / 32, 256, 0, stream>>>(
            q2ps, l2ps, lens, c_prU, zq, zl, sps, pss);
        k_queue_update<<<NQ_ / 4, 256, 0, stream>>>(
            p2qs, p2q_deg, c_qrW, c_qrU, c_qrB, c_prW, c_prB,
            pss, queue_state, zq);
        k_link_update<<<NL_ / 4, 256, 0, stream>>>(
            q2l, c_lrW, c_lrU, c_lrB, c_prW + 1024,
            queue_state, link_state, zl);
    }

    // iteration 7: rnn with fused readout; final qupd/lupd are dead in the ref
    k_rnn_last<<<(P_ + 31) / 32, 256, 0, stream>>>(
        q2ps, l2ps, lens, perm, c_prU, zq, zl, sps,
        c_capacity, c_traffic, c_packets,
        c_ro_w1, c_ro_b1, c_ro_w2, c_ro_b2, c_ro_w3, c_ro_b3,
        flags, d_out);
}